// Round 17
// baseline (571.443 us; speedup 1.0000x reference)
//
#include <hip/hip_runtime.h>
#include <math.h>

#define BB 64
#define NN 8732
#define NV4 (NN / 4)
#define CC 21
#define TB 256
#define GX 35
#define PREP 8       // probe repeat: guarantees every probe > 39us fills
#define TOT (BB * NN)  // 558848 = 2183*256

// Monotonic float->uint mapping (total order)
static __device__ __forceinline__ unsigned f2u(float f) {
  unsigned u = __float_as_uint(f);
  return (u & 0x80000000u) ? ~u : (u | 0x80000000u);
}

// Shared compute body (R16 form, native transcendentals).
static __device__ __forceinline__ void box_compute(
    const float* pr, const float* lr, const float4 a, const float4 p,
    unsigned& key, float& cp, float& h, int& isPos) {
  isPos = (a.x != 0.f) || (a.y != 0.f) || (a.z != 0.f) || (a.w != 0.f);
  float ssum = 0.f, tdot = 0.f, es = 0.f;
#pragma unroll
  for (int j = 0; j < CC; ++j) {
    const float v = pr[j];
    ssum += v;
    tdot = fmaf(lr[j], v, tdot);
    es += __expf(v);
  }
  const float pt = tdot / ssum;
  const float ptc = fminf(fmaxf(pt, 1e-7f), 1.0f - 1e-7f);
  cp = -__logf(ptc);
  const float cel = __logf(es) - tdot;
  key = isPos ? 0u : f2u(cel);
  const float dx = p.x - a.x, dy = p.y - a.y, dz = p.z - a.z, dw = p.w - a.w;
  const float ax = fabsf(dx), ay = fabsf(dy), az = fabsf(dz), aw = fabsf(dw);
  h = (ax <= 1.f ? 0.5f * dx * dx : ax - 0.5f)
    + (ay <= 1.f ? 0.5f * dy * dy : ay - 0.5f)
    + (az <= 1.f ? 0.5f * dz * dz : az - 0.5f)
    + (aw <= 1.f ? 0.5f * dw * dw : aw - 0.5f);
}

// ---- kP0: loads + sum only (kD replica, measured directly) ----
__global__ __launch_bounds__(256) void kP0(
    const float* __restrict__ abd, const float* __restrict__ lbl,
    const float* __restrict__ pbd, const float* __restrict__ plog,
    float* __restrict__ decoy) {
  const int i0 = blockIdx.x * 256 + threadIdx.x;
  float s = 0.f;
  for (int r = 0; r < PREP; ++r) {
    const int i = (i0 + r * 131072) % TOT;
    const float* pr = plog + (size_t)i * CC;
    const float* lr = lbl + (size_t)i * CC;
#pragma unroll
    for (int j = 0; j < CC; ++j) s += pr[j] + lr[j];
    const float4 a = reinterpret_cast<const float4*>(abd)[i];
    const float4 p = reinterpret_cast<const float4*>(pbd)[i];
    s += a.x + a.y + a.z + a.w + p.x + p.y + p.z + p.w;
  }
  for (int o = 32; o > 0; o >>= 1) s += __shfl_down(s, o, 64);
  if ((threadIdx.x & 63) == 0) decoy[blockIdx.x * 4 + (threadIdx.x >> 6)] = s;
}

// ---- kP1: + full compute, NO global stores ----
__global__ __launch_bounds__(256) void kP1(
    const float* __restrict__ abd, const float* __restrict__ lbl,
    const float* __restrict__ pbd, const float* __restrict__ plog,
    float* __restrict__ decoy) {
  const int i0 = blockIdx.x * 256 + threadIdx.x;
  float s = 0.f;
  for (int r = 0; r < PREP; ++r) {
    const int i = (i0 + r * 131072) % TOT;
    const float4 a = reinterpret_cast<const float4*>(abd)[i];
    const float4 p = reinterpret_cast<const float4*>(pbd)[i];
    unsigned key; float cp, h; int isPos;
    box_compute(plog + (size_t)i * CC, lbl + (size_t)i * CC, a, p, key, cp, h, isPos);
    s += cp + h + (float)(key & 255u) + (float)isPos;
  }
  for (int o = 32; o > 0; o >>= 1) s += __shfl_down(s, o, 64);
  if ((threadIdx.x & 63) == 0) decoy[blockIdx.x * 4 + (threadIdx.x >> 6)] = s;
}

// ---- kP2: + keys/cep global stores (real k1 function, flat 1D shell) ----
__global__ __launch_bounds__(256) void kP2(
    const float* __restrict__ abd, const float* __restrict__ lbl,
    const float* __restrict__ pbd, const float* __restrict__ plog,
    unsigned* __restrict__ keys, float* __restrict__ cep,
    float* __restrict__ decoy) {
  const int i0 = blockIdx.x * 256 + threadIdx.x;
  float s = 0.f;
  for (int r = 0; r < PREP; ++r) {
    const int i = (i0 + r * 131072) % TOT;
    const float4 a = reinterpret_cast<const float4*>(abd)[i];
    const float4 p = reinterpret_cast<const float4*>(pbd)[i];
    unsigned key; float cp, h; int isPos;
    box_compute(plog + (size_t)i * CC, lbl + (size_t)i * CC, a, p, key, cp, h, isPos);
    keys[i] = key;
    cep[i] = cp;
    s += cp + h + (float)isPos;
  }
  for (int o = 32; o > 0; o >>= 1) s += __shfl_down(s, o, 64);
  if ((threadIdx.x & 63) == 0) decoy[blockIdx.x * 4 + (threadIdx.x >> 6)] = s;
}

// ---- kP4: exact R16 k1 shell (2D grid, barrier reduce) in a REP loop ----
__global__ __launch_bounds__(256) void kP4(
    const float* __restrict__ abd, const float* __restrict__ lbl,
    const float* __restrict__ pbd, const float* __restrict__ plog,
    unsigned* __restrict__ keys, float* __restrict__ cep,
    float* __restrict__ dpl, float* __restrict__ dpc, int* __restrict__ dpcnt) {
  __shared__ float s_l[4], s_p[4];
  __shared__ int s_c[4];
  const int b = blockIdx.y;
  const int tid = threadIdx.x;
  const int lane = tid & 63, wv = tid >> 6;
  for (int r = 0; r < PREP; ++r) {
    const int n = (blockIdx.x * TB + tid + r * 257) % NN;  // rotated, valid
    const size_t idx = (size_t)b * NN + n;
    const float4 a = reinterpret_cast<const float4*>(abd)[idx];
    const float4 p = reinterpret_cast<const float4*>(pbd)[idx];
    unsigned key; float cp, h; int isPos;
    box_compute(plog + idx * CC, lbl + idx * CC, a, p, key, cp, h, isPos);
    keys[idx] = key;
    cep[idx] = cp;
    float loc = isPos ? h * 0.25f : 0.f;
    float pconf = isPos ? cp : 0.f;
    int pctr = isPos;
    for (int off = 32; off > 0; off >>= 1) {
      loc += __shfl_down(loc, off, 64);
      pconf += __shfl_down(pconf, off, 64);
      pctr += __shfl_down(pctr, off, 64);
    }
    if (lane == 0) { s_l[wv] = loc; s_p[wv] = pconf; s_c[wv] = pctr; }
    __syncthreads();
    if (tid == 0) {
      const int bi = b * GX + blockIdx.x;
      dpl[bi] = s_l[0] + s_l[1] + s_l[2] + s_l[3];
      dpc[bi] = s_p[0] + s_p[1] + s_p[2] + s_p[3];
      dpcnt[bi] = s_c[0] + s_c[1] + s_c[2] + s_c[3];
    }
    __syncthreads();
  }
}

// ---- real k1 (R16, unchanged) ----
__global__ __launch_bounds__(256) void k1_map(
    const float* __restrict__ abd, const float* __restrict__ lbl,
    const float* __restrict__ pbd, const float* __restrict__ plog,
    unsigned* __restrict__ keys, float* __restrict__ cep,
    float* __restrict__ pl, float* __restrict__ pc, int* __restrict__ pcnt) {
  __shared__ float s_l[4], s_p[4];
  __shared__ int s_c[4];
  const int b = blockIdx.y;
  const int n = blockIdx.x * TB + threadIdx.x;
  const int tid = threadIdx.x;
  const bool valid = n < NN;
  float loc = 0.f, pconf = 0.f;
  int isPos = 0;
  if (valid) {
    const size_t idx = (size_t)b * NN + n;
    const float4 a = reinterpret_cast<const float4*>(abd)[idx];
    const float4 p = reinterpret_cast<const float4*>(pbd)[idx];
    unsigned key; float cp, h;
    box_compute(plog + idx * CC, lbl + idx * CC, a, p, key, cp, h, isPos);
    keys[idx] = key;
    cep[idx] = cp;
    pconf = isPos ? cp : 0.f;
    loc = isPos ? h * 0.25f : 0.f;
  }
  float lvv = loc, pcf = pconf;
  int pctr = isPos;
  for (int off = 32; off > 0; off >>= 1) {
    lvv += __shfl_down(lvv, off, 64);
    pcf += __shfl_down(pcf, off, 64);
    pctr += __shfl_down(pctr, off, 64);
  }
  const int lane = tid & 63, wv = tid >> 6;
  if (lane == 0) { s_l[wv] = lvv; s_p[wv] = pcf; s_c[wv] = pctr; }
  __syncthreads();
  if (tid == 0) {
    const int bi = b * GX + blockIdx.x;
    pl[bi] = s_l[0] + s_l[1] + s_l[2] + s_l[3];
    pc[bi] = s_p[0] + s_p[1] + s_p[2] + s_p[3];
    pcnt[bi] = s_c[0] + s_c[1] + s_c[2] + s_c[3];
  }
}

// Kernel 2: per-row partial-reduce + exact radix-select (unchanged).
#define K2T 1024
#define K2W 16

__global__ __launch_bounds__(K2T) void k2_select(
    const unsigned* __restrict__ keys, const float* __restrict__ cep,
    const float* __restrict__ pl, const float* __restrict__ pc,
    const int* __restrict__ pcnt,
    double* __restrict__ row_loc, double* __restrict__ row_conf,
    int* __restrict__ row_pos) {
  __shared__ unsigned hist[2048];
  __shared__ unsigned wsum[K2W];
  __shared__ unsigned bc[2];
  __shared__ unsigned wtot[K2W];
  __shared__ double s_d[K2W];
  __shared__ double s_rl, s_rc;
  __shared__ int s_pos;
  const int b = blockIdx.x;
  const int tid = threadIdx.x;
  const int lane = tid & 63, wv = tid >> 6;

  if (wv == 0) {
    float a = 0.f, c = 0.f;
    int p = 0;
    if (lane < GX) {
      a = pl[b * GX + lane];
      c = pc[b * GX + lane];
      p = pcnt[b * GX + lane];
    }
    for (int off = 32; off > 0; off >>= 1) {
      a += __shfl_down(a, off, 64);
      c += __shfl_down(c, off, 64);
      p += __shfl_down(p, off, 64);
    }
    if (lane == 0) { s_rl = (double)a; s_rc = (double)c; s_pos = p; }
  }
  __syncthreads();
  const int pos = s_pos;
  unsigned k = (unsigned)(pos * 3);
  const unsigned negs = (unsigned)(NN - pos);
  if (k > negs) k = negs;

  double neg_total = 0.0;
  if (k > 0) {
    const unsigned* rk = keys + (size_t)b * NN;
    const uint4* rk4 = reinterpret_cast<const uint4*>(rk);
    unsigned want = k;
    unsigned prefix = 0;
    for (int pass = 0; pass < 3; ++pass) {
      const int nb = (pass == 2) ? 1024 : 2048;
      const int shift = (pass == 0) ? 21 : (pass == 1) ? 10 : 0;
      for (int i = tid; i < nb; i += K2T) hist[i] = 0;
      __syncthreads();
      if (pass == 0) {
        for (int t = tid; t < NV4; t += K2T) {
          uint4 v = rk4[t];
          atomicAdd(&hist[v.x >> 21], 1u);
          atomicAdd(&hist[v.y >> 21], 1u);
          atomicAdd(&hist[v.z >> 21], 1u);
          atomicAdd(&hist[v.w >> 21], 1u);
        }
      } else {
        const unsigned pshift = (pass == 1) ? 21u : 10u;
        const unsigned msk = (unsigned)(nb - 1);
        for (int t = tid; t < NV4; t += K2T) {
          uint4 v = rk4[t];
          if ((v.x >> pshift) == prefix) atomicAdd(&hist[(v.x >> shift) & msk], 1u);
          if ((v.y >> pshift) == prefix) atomicAdd(&hist[(v.y >> shift) & msk], 1u);
          if ((v.z >> pshift) == prefix) atomicAdd(&hist[(v.z >> shift) & msk], 1u);
          if ((v.w >> pshift) == prefix) atomicAdd(&hist[(v.w >> shift) & msk], 1u);
        }
      }
      __syncthreads();
      const int PR = nb / K2T;
      unsigned v0, v1 = 0, ls;
      if (PR == 2) {
        v0 = hist[nb - 1 - (tid * 2)];
        v1 = hist[nb - 1 - (tid * 2 + 1)];
        ls = v0 + v1;
      } else {
        v0 = hist[nb - 1 - tid];
        ls = v0;
      }
      unsigned x = ls;
#pragma unroll
      for (int off = 1; off < 64; off <<= 1) {
        unsigned y = __shfl_up(x, off, 64);
        if (lane >= off) x += y;
      }
      if (lane == 63) wsum[wv] = x;
      __syncthreads();
      if (wv == 0 && lane < K2W) {
        unsigned wx = wsum[lane];
#pragma unroll
        for (int off = 1; off < K2W; off <<= 1) {
          unsigned wy = __shfl_up(wx, off, K2W);
          if ((lane & (K2W - 1)) >= off) wx += wy;
        }
        wsum[lane] = wx;
      }
      __syncthreads();
      const unsigned woff = (wv == 0) ? 0u : wsum[wv - 1];
      const unsigned pinc = woff + x;
      if (PR == 2) {
        const unsigned p0 = pinc - ls + v0;
        const unsigned p1 = pinc;
        if (v0 > 0 && p0 >= want && p0 - v0 < want) { bc[0] = (unsigned)(nb - 1 - tid * 2); bc[1] = want - (p0 - v0); }
        if (v1 > 0 && p1 >= want && p1 - v1 < want) { bc[0] = (unsigned)(nb - 1 - (tid * 2 + 1)); bc[1] = want - (p1 - v1); }
      } else {
        if (v0 > 0 && pinc >= want && pinc - v0 < want) { bc[0] = (unsigned)(nb - 1 - tid); bc[1] = want - (pinc - v0); }
      }
      __syncthreads();
      const unsigned d = bc[0];
      want = bc[1];
      prefix = (pass == 0) ? d : ((prefix << ((pass == 1) ? 11 : 10)) | d);
      __syncthreads();
    }
    const unsigned tau = prefix;
    const unsigned neq = want;

    const float* rc = cep + (size_t)b * NN;
    double mysum = 0.0;
    unsigned bbase = 0;
    for (int start = 0; start < NN; start += K2T) {
      const int i = start + tid;
      const unsigned key = (i < NN) ? rk[i] : 0u;
      const bool gt = (i < NN) && (key > tau);
      const bool eq = (i < NN) && (key == tau);
      if (gt) mysum += (double)rc[i];
      const unsigned long long mb = __ballot(eq);
      if (lane == 0) wtot[wv] = (unsigned)__popcll(mb);
      __syncthreads();
      unsigned wpref = 0, tot = 0;
#pragma unroll
      for (int w = 0; w < K2W; ++w) {
        const unsigned c = wtot[w];
        wpref += (w < wv) ? c : 0u;
        tot += c;
      }
      if (eq) {
        const unsigned lanepref = (unsigned)__popcll(mb & ((1ull << lane) - 1ull));
        if (bbase + wpref + lanepref < neq) mysum += (double)rc[i];
      }
      bbase += tot;
      __syncthreads();
    }
    for (int off = 32; off > 0; off >>= 1) mysum += __shfl_down(mysum, off, 64);
    if (lane == 0) s_d[wv] = mysum;
    __syncthreads();
    if (tid == 0) {
#pragma unroll
      for (int w = 0; w < K2W; ++w) neg_total += s_d[w];
    }
  }
  if (tid == 0) {
    row_loc[b] = s_rl;
    row_conf[b] = s_rc + neg_total;
    row_pos[b] = pos;
  }
}

// Kernel 3: finalize.
__global__ void k3_final(const double* __restrict__ row_loc,
                         const double* __restrict__ row_conf,
                         const int* __restrict__ row_pos,
                         float* __restrict__ out) {
  const int lane = threadIdx.x;
  double l = row_loc[lane], c = row_conf[lane];
  int p = row_pos[lane];
  for (int off = 32; off > 0; off >>= 1) {
    l += __shfl_down(l, off, 64);
    c += __shfl_down(c, off, 64);
    p += __shfl_down(p, off, 64);
  }
  if (lane == 0) {
    const double tot = (p > 0) ? (double)p : 1.0;
    out[0] = (float)(l / tot);
    out[1] = (float)(c / tot);
  }
}

extern "C" void kernel_launch(void* const* d_in, const int* in_sizes, int n_in,
                              void* d_out, int out_size, void* d_ws, size_t ws_size,
                              hipStream_t stream) {
  const float* abd = (const float*)d_in[0];
  const float* lbl = (const float*)d_in[1];
  const float* pbd = (const float*)d_in[2];
  const float* plog = (const float*)d_in[3];

  char* ws = (char*)d_ws;
  float* pl = (float*)(ws + 0);              // [2240]
  float* pc = (float*)(ws + 8960);           // [2240]
  int* pcnt = (int*)(ws + 17920);            // [2240]
  double* row_loc = (double*)(ws + 26880);   // [64]
  double* row_conf = (double*)(ws + 27392);  // [64]
  int* row_pos = (int*)(ws + 27904);         // [64]
  unsigned* keys = (unsigned*)(ws + 28160);  // [B*N]
  float* cep = (float*)(ws + 2263552);       // [B*N]
  float* decoy = (float*)(ws + 4498944);     // [8732]
  float* dpl = (float*)(ws + 4534912);       // [2240]
  float* dpc = (float*)(ws + 4543872);       // [2240]
  int* dpcnt = (int*)(ws + 4552832);         // [2240]

  dim3 g2(GX, BB);
  // ---- probes (keys/cep scribbled; real k1 rewrites them after) ----
  kP0<<<2183, 256, 0, stream>>>(abd, lbl, pbd, plog, decoy);
  kP1<<<2183, 256, 0, stream>>>(abd, lbl, pbd, plog, decoy);
  kP2<<<2183, 256, 0, stream>>>(abd, lbl, pbd, plog, keys, cep, decoy);
  kP4<<<g2, TB, 0, stream>>>(abd, lbl, pbd, plog, keys, cep, dpl, dpc, dpcnt);
  // ---- real pipeline ----
  k1_map<<<g2, TB, 0, stream>>>(abd, lbl, pbd, plog, keys, cep, pl, pc, pcnt);
  k2_select<<<BB, K2T, 0, stream>>>(keys, cep, pl, pc, pcnt, row_loc, row_conf, row_pos);
  k3_final<<<1, 64, 0, stream>>>(row_loc, row_conf, row_pos, (float*)d_out);
}

// Round 19
// 71.450 us; speedup vs baseline: 7.9978x; 7.9978x over previous
//
#include <hip/hip_runtime.h>
#include <math.h>

#define BB 64
#define NN 8732
#define NV4 (NN / 4)  // 2183
#define CC 21
#define TB 256        // boxes per k1 block
#define GX 35         // k1 blocks per row = ceil(8732/256)

typedef float vf4 __attribute__((ext_vector_type(4)));  // clang-native: nt-load OK

// Monotonic float->uint mapping (total order)
static __device__ __forceinline__ unsigned f2u(float f) {
  unsigned u = __float_as_uint(f);
  return (u & 0x80000000u) ? ~u : (u | 0x80000000u);
}

// Kernel 1: R16 single-pass map with NON-TEMPORAL input loads.
// R17 probe model: marginal sweep = 15-17us, but every structure pays a
// ~26us FIRST-TOUCH premium — the harness's 268MB reset-fill thrashes L3
// (dirty lines) between every timed replay, so replays are always
// first-touch. Theory: the premium is dirty-line eviction (each input
// line allocated into L3 evicts a dirty fill line -> ~112MB writeback
// shadow). nt loads bypass cache allocation -> pure 112MB read.
// Values bit-identical to R16 (absmax 0.0 expected).
__global__ __launch_bounds__(256) void k1_map(
    const float* __restrict__ abd, const float* __restrict__ lbl,
    const float* __restrict__ pbd, const float* __restrict__ plog,
    unsigned* __restrict__ keys, float* __restrict__ cep,
    float* __restrict__ pl, float* __restrict__ pc, int* __restrict__ pcnt) {
  __shared__ float s_l[4], s_p[4];
  __shared__ int s_c[4];

  const int b = blockIdx.y;
  const int n = blockIdx.x * TB + threadIdx.x;
  const int tid = threadIdx.x;
  const bool valid = n < NN;
  float loc = 0.f, pconf = 0.f;
  int isPos = 0;
  if (valid) {
    const size_t idx = (size_t)b * NN + n;
    const vf4 a =
        __builtin_nontemporal_load(reinterpret_cast<const vf4*>(abd) + idx);
    const vf4 p =
        __builtin_nontemporal_load(reinterpret_cast<const vf4*>(pbd) + idx);
    isPos = (a.x != 0.f) || (a.y != 0.f) || (a.z != 0.f) || (a.w != 0.f);

    const float* pr = plog + idx * CC;
    const float* lr = lbl + idx * CC;
    // ---- ONE pass: sum, one-hot dot, exp-sum (no max shift) ----
    float ssum = 0.f, tdot = 0.f, es = 0.f;
#pragma unroll
    for (int j = 0; j < CC; ++j) {
      const float v = __builtin_nontemporal_load(pr + j);
      const float lv = __builtin_nontemporal_load(lr + j);
      ssum += v;
      tdot = fmaf(lv, v, tdot);  // labels exact one-hot
      es += __expf(v);           // native v_exp_f32
    }
    const float pt = tdot / ssum;
    const float ptc = fminf(fmaxf(pt, 1e-7f), 1.0f - 1e-7f);
    const float cp = -__logf(ptc);        // conf CE (native log)
    const float cel = __logf(es) - tdot;  // mining key = logsumexp - logit_t
    __builtin_nontemporal_store(isPos ? 0u : f2u(cel), keys + idx);
    __builtin_nontemporal_store(cp, cep + idx);
    pconf = isPos ? cp : 0.f;
    const float dx = p.x - a.x, dy = p.y - a.y, dz = p.z - a.z, dw = p.w - a.w;
    const float ax = fabsf(dx), ay = fabsf(dy), az = fabsf(dz), aw = fabsf(dw);
    const float h = (ax <= 1.f ? 0.5f * dx * dx : ax - 0.5f)
                  + (ay <= 1.f ? 0.5f * dy * dy : ay - 0.5f)
                  + (az <= 1.f ? 0.5f * dz * dz : az - 0.5f)
                  + (aw <= 1.f ? 0.5f * dw * dw : aw - 0.5f);
    loc = isPos ? h * 0.25f : 0.f;
  }
  float lvv = loc, pcf = pconf;
  int pctr = isPos;
  for (int off = 32; off > 0; off >>= 1) {
    lvv += __shfl_down(lvv, off, 64);
    pcf += __shfl_down(pcf, off, 64);
    pctr += __shfl_down(pctr, off, 64);
  }
  const int lane = tid & 63, wv = tid >> 6;
  if (lane == 0) { s_l[wv] = lvv; s_p[wv] = pcf; s_c[wv] = pctr; }
  __syncthreads();
  if (tid == 0) {
    const int bi = b * GX + blockIdx.x;
    pl[bi] = s_l[0] + s_l[1] + s_l[2] + s_l[3];
    pc[bi] = s_p[0] + s_p[1] + s_p[2] + s_p[3];
    pcnt[bi] = s_c[0] + s_c[1] + s_c[2] + s_c[3];
  }
}

// Kernel 2: per-row partial-reduce + exact radix-select (R4 core, GX=35).
#define K2T 1024
#define K2W 16

__global__ __launch_bounds__(K2T) void k2_select(
    const unsigned* __restrict__ keys, const float* __restrict__ cep,
    const float* __restrict__ pl, const float* __restrict__ pc,
    const int* __restrict__ pcnt,
    double* __restrict__ row_loc, double* __restrict__ row_conf,
    int* __restrict__ row_pos) {
  __shared__ unsigned hist[2048];
  __shared__ unsigned wsum[K2W];
  __shared__ unsigned bc[2];
  __shared__ unsigned wtot[K2W];
  __shared__ double s_d[K2W];
  __shared__ double s_rl, s_rc;
  __shared__ int s_pos;
  const int b = blockIdx.x;
  const int tid = threadIdx.x;
  const int lane = tid & 63, wv = tid >> 6;

  if (wv == 0) {
    float a = 0.f, c = 0.f;
    int p = 0;
    if (lane < GX) {
      a = pl[b * GX + lane];
      c = pc[b * GX + lane];
      p = pcnt[b * GX + lane];
    }
    for (int off = 32; off > 0; off >>= 1) {
      a += __shfl_down(a, off, 64);
      c += __shfl_down(c, off, 64);
      p += __shfl_down(p, off, 64);
    }
    if (lane == 0) { s_rl = (double)a; s_rc = (double)c; s_pos = p; }
  }
  __syncthreads();
  const int pos = s_pos;
  unsigned k = (unsigned)(pos * 3);
  const unsigned negs = (unsigned)(NN - pos);
  if (k > negs) k = negs;

  double neg_total = 0.0;
  if (k > 0) {  // block-uniform branch
    const unsigned* rk = keys + (size_t)b * NN;
    const uint4* rk4 = reinterpret_cast<const uint4*>(rk);
    unsigned want = k;
    unsigned prefix = 0;
    for (int pass = 0; pass < 3; ++pass) {
      const int nb = (pass == 2) ? 1024 : 2048;
      const int shift = (pass == 0) ? 21 : (pass == 1) ? 10 : 0;
      for (int i = tid; i < nb; i += K2T) hist[i] = 0;
      __syncthreads();
      if (pass == 0) {
        for (int t = tid; t < NV4; t += K2T) {
          uint4 v = rk4[t];
          atomicAdd(&hist[v.x >> 21], 1u);
          atomicAdd(&hist[v.y >> 21], 1u);
          atomicAdd(&hist[v.z >> 21], 1u);
          atomicAdd(&hist[v.w >> 21], 1u);
        }
      } else {
        const unsigned pshift = (pass == 1) ? 21u : 10u;
        const unsigned msk = (unsigned)(nb - 1);
        for (int t = tid; t < NV4; t += K2T) {
          uint4 v = rk4[t];
          if ((v.x >> pshift) == prefix) atomicAdd(&hist[(v.x >> shift) & msk], 1u);
          if ((v.y >> pshift) == prefix) atomicAdd(&hist[(v.y >> shift) & msk], 1u);
          if ((v.z >> pshift) == prefix) atomicAdd(&hist[(v.z >> shift) & msk], 1u);
          if ((v.w >> pshift) == prefix) atomicAdd(&hist[(v.w >> shift) & msk], 1u);
        }
      }
      __syncthreads();
      const int PR = nb / K2T;
      unsigned v0, v1 = 0, ls;
      if (PR == 2) {
        v0 = hist[nb - 1 - (tid * 2)];
        v1 = hist[nb - 1 - (tid * 2 + 1)];
        ls = v0 + v1;
      } else {
        v0 = hist[nb - 1 - tid];
        ls = v0;
      }
      unsigned x = ls;
#pragma unroll
      for (int off = 1; off < 64; off <<= 1) {
        unsigned y = __shfl_up(x, off, 64);
        if (lane >= off) x += y;
      }
      if (lane == 63) wsum[wv] = x;
      __syncthreads();
      if (wv == 0 && lane < K2W) {
        unsigned wx = wsum[lane];
#pragma unroll
        for (int off = 1; off < K2W; off <<= 1) {
          unsigned wy = __shfl_up(wx, off, K2W);
          if ((lane & (K2W - 1)) >= off) wx += wy;
        }
        wsum[lane] = wx;
      }
      __syncthreads();
      const unsigned woff = (wv == 0) ? 0u : wsum[wv - 1];
      const unsigned pinc = woff + x;
      if (PR == 2) {
        const unsigned p0 = pinc - ls + v0;
        const unsigned p1 = pinc;
        if (v0 > 0 && p0 >= want && p0 - v0 < want) { bc[0] = (unsigned)(nb - 1 - tid * 2); bc[1] = want - (p0 - v0); }
        if (v1 > 0 && p1 >= want && p1 - v1 < want) { bc[0] = (unsigned)(nb - 1 - (tid * 2 + 1)); bc[1] = want - (p1 - v1); }
      } else {
        if (v0 > 0 && pinc >= want && pinc - v0 < want) { bc[0] = (unsigned)(nb - 1 - tid); bc[1] = want - (pinc - v0); }
      }
      __syncthreads();
      const unsigned d = bc[0];
      want = bc[1];
      prefix = (pass == 0) ? d : ((prefix << ((pass == 1) ? 11 : 10)) | d);
      __syncthreads();
    }
    const unsigned tau = prefix;
    const unsigned neq = want;

    const float* rc = cep + (size_t)b * NN;
    double mysum = 0.0;
    unsigned bbase = 0;
    for (int start = 0; start < NN; start += K2T) {
      const int i = start + tid;
      const unsigned key = (i < NN) ? rk[i] : 0u;
      const bool gt = (i < NN) && (key > tau);
      const bool eq = (i < NN) && (key == tau);
      if (gt) mysum += (double)rc[i];
      const unsigned long long mb = __ballot(eq);
      if (lane == 0) wtot[wv] = (unsigned)__popcll(mb);
      __syncthreads();
      unsigned wpref = 0, tot = 0;
#pragma unroll
      for (int w = 0; w < K2W; ++w) {
        const unsigned c = wtot[w];
        wpref += (w < wv) ? c : 0u;
        tot += c;
      }
      if (eq) {
        const unsigned lanepref = (unsigned)__popcll(mb & ((1ull << lane) - 1ull));
        if (bbase + wpref + lanepref < neq) mysum += (double)rc[i];
      }
      bbase += tot;
      __syncthreads();
    }
    for (int off = 32; off > 0; off >>= 1) mysum += __shfl_down(mysum, off, 64);
    if (lane == 0) s_d[wv] = mysum;
    __syncthreads();
    if (tid == 0) {
#pragma unroll
      for (int w = 0; w < K2W; ++w) neg_total += s_d[w];
    }
  }
  if (tid == 0) {
    row_loc[b] = s_rl;
    row_conf[b] = s_rc + neg_total;
    row_pos[b] = pos;
  }
}

// Kernel 3: reduce 64 rows, finalize the two scalars.
__global__ void k3_final(const double* __restrict__ row_loc,
                         const double* __restrict__ row_conf,
                         const int* __restrict__ row_pos,
                         float* __restrict__ out) {
  const int lane = threadIdx.x;  // 64 threads
  double l = row_loc[lane], c = row_conf[lane];
  int p = row_pos[lane];
  for (int off = 32; off > 0; off >>= 1) {
    l += __shfl_down(l, off, 64);
    c += __shfl_down(c, off, 64);
    p += __shfl_down(p, off, 64);
  }
  if (lane == 0) {
    const double tot = (p > 0) ? (double)p : 1.0;
    out[0] = (float)(l / tot);
    out[1] = (float)(c / tot);
  }
}

extern "C" void kernel_launch(void* const* d_in, const int* in_sizes, int n_in,
                              void* d_out, int out_size, void* d_ws, size_t ws_size,
                              hipStream_t stream) {
  const float* abd = (const float*)d_in[0];
  const float* lbl = (const float*)d_in[1];
  const float* pbd = (const float*)d_in[2];
  const float* plog = (const float*)d_in[3];

  char* ws = (char*)d_ws;
  float* pl = (float*)(ws + 0);              // [BB*GX] = 2240
  float* pc = (float*)(ws + 8960);           // [2240]
  int* pcnt = (int*)(ws + 17920);            // [2240]
  double* row_loc = (double*)(ws + 26880);   // [64]
  double* row_conf = (double*)(ws + 27392);  // [64]
  int* row_pos = (int*)(ws + 27904);         // [64]
  unsigned* keys = (unsigned*)(ws + 28160);  // [B*N], 16B-aligned
  float* cep = (float*)(ws + 28160 + (size_t)BB * NN * sizeof(unsigned));

  // All scratch is written unconditionally before being read -> no memset.
  dim3 g1(GX, BB);
  k1_map<<<g1, TB, 0, stream>>>(abd, lbl, pbd, plog, keys, cep, pl, pc, pcnt);
  k2_select<<<BB, K2T, 0, stream>>>(keys, cep, pl, pc, pcnt, row_loc, row_conf, row_pos);
  k3_final<<<1, 64, 0, stream>>>(row_loc, row_conf, row_pos, (float*)d_out);
}

// Round 20
// 40.507 us; speedup vs baseline: 14.1071x; 1.7639x over previous
//
#include <hip/hip_runtime.h>
#include <math.h>

#define BB 64
#define NN 8732
#define NV4 (NN / 4)  // 2183
#define CC 21
#define TB 256        // boxes per k1 block
#define GX 35         // k1 blocks per row = ceil(8732/256)

// Monotonic float->uint mapping (total order)
static __device__ __forceinline__ unsigned f2u(float f) {
  unsigned u = __float_as_uint(f);
  return (u & 0x80000000u) ? ~u : (u | 0x80000000u);
}

// Kernel 1 (FINAL = R16 form): single-pass per-box map, cached loads,
// native transcendentals, no max-shift (logits ~N(0,1): sum(exp) f32-safe,
// log(sum(exp))-tdot == shifted form). R19 showed nt-loads amplify fetch
// 1.5x (84B rows straddle 64B lines; bypass loses the shared-line reuse).
// Ceiling model (R17 probes + R12 kA + R19 fetch): replay-regime traffic =
// 121MB read + ~112MB dirty-L3 writeback shadow (harness re-poisons 268MB
// ws between replays) ~ 34-37us; measured k1 ~39-43us => within ~10%.
__global__ __launch_bounds__(256) void k1_map(
    const float* __restrict__ abd, const float* __restrict__ lbl,
    const float* __restrict__ pbd, const float* __restrict__ plog,
    unsigned* __restrict__ keys, float* __restrict__ cep,
    float* __restrict__ pl, float* __restrict__ pc, int* __restrict__ pcnt) {
  __shared__ float s_l[4], s_p[4];
  __shared__ int s_c[4];

  const int b = blockIdx.y;
  const int n = blockIdx.x * TB + threadIdx.x;
  const int tid = threadIdx.x;
  const bool valid = n < NN;
  float loc = 0.f, pconf = 0.f;
  int isPos = 0;
  if (valid) {
    const size_t idx = (size_t)b * NN + n;
    const float4 a = reinterpret_cast<const float4*>(abd)[idx];
    const float4 p = reinterpret_cast<const float4*>(pbd)[idx];
    isPos = (a.x != 0.f) || (a.y != 0.f) || (a.z != 0.f) || (a.w != 0.f);

    const float* pr = plog + idx * CC;
    const float* lr = lbl + idx * CC;
    // ---- ONE pass: sum, one-hot dot, exp-sum (no max shift) ----
    float ssum = 0.f, tdot = 0.f, es = 0.f;
#pragma unroll
    for (int j = 0; j < CC; ++j) {
      const float v = pr[j];
      ssum += v;
      tdot = fmaf(lr[j], v, tdot);  // labels exact one-hot
      es += __expf(v);              // native v_exp_f32
    }
    const float pt = tdot / ssum;
    const float ptc = fminf(fmaxf(pt, 1e-7f), 1.0f - 1e-7f);
    const float cp = -__logf(ptc);        // conf CE (native log)
    const float cel = __logf(es) - tdot;  // mining key = logsumexp - logit_t
    keys[idx] = isPos ? 0u : f2u(cel);
    cep[idx] = cp;
    pconf = isPos ? cp : 0.f;
    const float dx = p.x - a.x, dy = p.y - a.y, dz = p.z - a.z, dw = p.w - a.w;
    const float ax = fabsf(dx), ay = fabsf(dy), az = fabsf(dz), aw = fabsf(dw);
    const float h = (ax <= 1.f ? 0.5f * dx * dx : ax - 0.5f)
                  + (ay <= 1.f ? 0.5f * dy * dy : ay - 0.5f)
                  + (az <= 1.f ? 0.5f * dz * dz : az - 0.5f)
                  + (aw <= 1.f ? 0.5f * dw * dw : aw - 0.5f);
    loc = isPos ? h * 0.25f : 0.f;
  }
  float lvv = loc, pcf = pconf;
  int pctr = isPos;
  for (int off = 32; off > 0; off >>= 1) {
    lvv += __shfl_down(lvv, off, 64);
    pcf += __shfl_down(pcf, off, 64);
    pctr += __shfl_down(pctr, off, 64);
  }
  const int lane = tid & 63, wv = tid >> 6;
  if (lane == 0) { s_l[wv] = lvv; s_p[wv] = pcf; s_c[wv] = pctr; }
  __syncthreads();
  if (tid == 0) {
    const int bi = b * GX + blockIdx.x;
    pl[bi] = s_l[0] + s_l[1] + s_l[2] + s_l[3];
    pc[bi] = s_p[0] + s_p[1] + s_p[2] + s_p[3];
    pcnt[bi] = s_c[0] + s_c[1] + s_c[2] + s_c[3];
  }
}

// Kernel 2: per-row partial-reduce + exact radix-select (R4 core, GX=35).
#define K2T 1024
#define K2W 16

__global__ __launch_bounds__(K2T) void k2_select(
    const unsigned* __restrict__ keys, const float* __restrict__ cep,
    const float* __restrict__ pl, const float* __restrict__ pc,
    const int* __restrict__ pcnt,
    double* __restrict__ row_loc, double* __restrict__ row_conf,
    int* __restrict__ row_pos) {
  __shared__ unsigned hist[2048];
  __shared__ unsigned wsum[K2W];
  __shared__ unsigned bc[2];
  __shared__ unsigned wtot[K2W];
  __shared__ double s_d[K2W];
  __shared__ double s_rl, s_rc;
  __shared__ int s_pos;
  const int b = blockIdx.x;
  const int tid = threadIdx.x;
  const int lane = tid & 63, wv = tid >> 6;

  if (wv == 0) {
    float a = 0.f, c = 0.f;
    int p = 0;
    if (lane < GX) {
      a = pl[b * GX + lane];
      c = pc[b * GX + lane];
      p = pcnt[b * GX + lane];
    }
    for (int off = 32; off > 0; off >>= 1) {
      a += __shfl_down(a, off, 64);
      c += __shfl_down(c, off, 64);
      p += __shfl_down(p, off, 64);
    }
    if (lane == 0) { s_rl = (double)a; s_rc = (double)c; s_pos = p; }
  }
  __syncthreads();
  const int pos = s_pos;
  unsigned k = (unsigned)(pos * 3);
  const unsigned negs = (unsigned)(NN - pos);
  if (k > negs) k = negs;

  double neg_total = 0.0;
  if (k > 0) {  // block-uniform branch
    const unsigned* rk = keys + (size_t)b * NN;
    const uint4* rk4 = reinterpret_cast<const uint4*>(rk);
    unsigned want = k;
    unsigned prefix = 0;
    for (int pass = 0; pass < 3; ++pass) {
      const int nb = (pass == 2) ? 1024 : 2048;
      const int shift = (pass == 0) ? 21 : (pass == 1) ? 10 : 0;
      for (int i = tid; i < nb; i += K2T) hist[i] = 0;
      __syncthreads();
      if (pass == 0) {
        for (int t = tid; t < NV4; t += K2T) {
          uint4 v = rk4[t];
          atomicAdd(&hist[v.x >> 21], 1u);
          atomicAdd(&hist[v.y >> 21], 1u);
          atomicAdd(&hist[v.z >> 21], 1u);
          atomicAdd(&hist[v.w >> 21], 1u);
        }
      } else {
        const unsigned pshift = (pass == 1) ? 21u : 10u;
        const unsigned msk = (unsigned)(nb - 1);
        for (int t = tid; t < NV4; t += K2T) {
          uint4 v = rk4[t];
          if ((v.x >> pshift) == prefix) atomicAdd(&hist[(v.x >> shift) & msk], 1u);
          if ((v.y >> pshift) == prefix) atomicAdd(&hist[(v.y >> shift) & msk], 1u);
          if ((v.z >> pshift) == prefix) atomicAdd(&hist[(v.z >> shift) & msk], 1u);
          if ((v.w >> pshift) == prefix) atomicAdd(&hist[(v.w >> shift) & msk], 1u);
        }
      }
      __syncthreads();
      const int PR = nb / K2T;
      unsigned v0, v1 = 0, ls;
      if (PR == 2) {
        v0 = hist[nb - 1 - (tid * 2)];
        v1 = hist[nb - 1 - (tid * 2 + 1)];
        ls = v0 + v1;
      } else {
        v0 = hist[nb - 1 - tid];
        ls = v0;
      }
      unsigned x = ls;
#pragma unroll
      for (int off = 1; off < 64; off <<= 1) {
        unsigned y = __shfl_up(x, off, 64);
        if (lane >= off) x += y;
      }
      if (lane == 63) wsum[wv] = x;
      __syncthreads();
      if (wv == 0 && lane < K2W) {
        unsigned wx = wsum[lane];
#pragma unroll
        for (int off = 1; off < K2W; off <<= 1) {
          unsigned wy = __shfl_up(wx, off, K2W);
          if ((lane & (K2W - 1)) >= off) wx += wy;
        }
        wsum[lane] = wx;
      }
      __syncthreads();
      const unsigned woff = (wv == 0) ? 0u : wsum[wv - 1];
      const unsigned pinc = woff + x;
      if (PR == 2) {
        const unsigned p0 = pinc - ls + v0;
        const unsigned p1 = pinc;
        if (v0 > 0 && p0 >= want && p0 - v0 < want) { bc[0] = (unsigned)(nb - 1 - tid * 2); bc[1] = want - (p0 - v0); }
        if (v1 > 0 && p1 >= want && p1 - v1 < want) { bc[0] = (unsigned)(nb - 1 - (tid * 2 + 1)); bc[1] = want - (p1 - v1); }
      } else {
        if (v0 > 0 && pinc >= want && pinc - v0 < want) { bc[0] = (unsigned)(nb - 1 - tid); bc[1] = want - (pinc - v0); }
      }
      __syncthreads();
      const unsigned d = bc[0];
      want = bc[1];
      prefix = (pass == 0) ? d : ((prefix << ((pass == 1) ? 11 : 10)) | d);
      __syncthreads();
    }
    const unsigned tau = prefix;
    const unsigned neq = want;

    const float* rc = cep + (size_t)b * NN;
    double mysum = 0.0;
    unsigned bbase = 0;
    for (int start = 0; start < NN; start += K2T) {
      const int i = start + tid;
      const unsigned key = (i < NN) ? rk[i] : 0u;
      const bool gt = (i < NN) && (key > tau);
      const bool eq = (i < NN) && (key == tau);
      if (gt) mysum += (double)rc[i];
      const unsigned long long mb = __ballot(eq);
      if (lane == 0) wtot[wv] = (unsigned)__popcll(mb);
      __syncthreads();
      unsigned wpref = 0, tot = 0;
#pragma unroll
      for (int w = 0; w < K2W; ++w) {
        const unsigned c = wtot[w];
        wpref += (w < wv) ? c : 0u;
        tot += c;
      }
      if (eq) {
        const unsigned lanepref = (unsigned)__popcll(mb & ((1ull << lane) - 1ull));
        if (bbase + wpref + lanepref < neq) mysum += (double)rc[i];
      }
      bbase += tot;
      __syncthreads();
    }
    for (int off = 32; off > 0; off >>= 1) mysum += __shfl_down(mysum, off, 64);
    if (lane == 0) s_d[wv] = mysum;
    __syncthreads();
    if (tid == 0) {
#pragma unroll
      for (int w = 0; w < K2W; ++w) neg_total += s_d[w];
    }
  }
  if (tid == 0) {
    row_loc[b] = s_rl;
    row_conf[b] = s_rc + neg_total;
    row_pos[b] = pos;
  }
}

// Kernel 3: reduce 64 rows, finalize the two scalars.
__global__ void k3_final(const double* __restrict__ row_loc,
                         const double* __restrict__ row_conf,
                         const int* __restrict__ row_pos,
                         float* __restrict__ out) {
  const int lane = threadIdx.x;  // 64 threads
  double l = row_loc[lane], c = row_conf[lane];
  int p = row_pos[lane];
  for (int off = 32; off > 0; off >>= 1) {
    l += __shfl_down(l, off, 64);
    c += __shfl_down(c, off, 64);
    p += __shfl_down(p, off, 64);
  }
  if (lane == 0) {
    const double tot = (p > 0) ? (double)p : 1.0;
    out[0] = (float)(l / tot);
    out[1] = (float)(c / tot);
  }
}

extern "C" void kernel_launch(void* const* d_in, const int* in_sizes, int n_in,
                              void* d_out, int out_size, void* d_ws, size_t ws_size,
                              hipStream_t stream) {
  const float* abd = (const float*)d_in[0];
  const float* lbl = (const float*)d_in[1];
  const float* pbd = (const float*)d_in[2];
  const float* plog = (const float*)d_in[3];

  char* ws = (char*)d_ws;
  float* pl = (float*)(ws + 0);              // [BB*GX] = 2240
  float* pc = (float*)(ws + 8960);           // [2240]
  int* pcnt = (int*)(ws + 17920);            // [2240]
  double* row_loc = (double*)(ws + 26880);   // [64]
  double* row_conf = (double*)(ws + 27392);  // [64]
  int* row_pos = (int*)(ws + 27904);         // [64]
  unsigned* keys = (unsigned*)(ws + 28160);  // [B*N], 16B-aligned
  float* cep = (float*)(ws + 28160 + (size_t)BB * NN * sizeof(unsigned));

  // All scratch is written unconditionally before being read -> no memset.
  dim3 g1(GX, BB);
  k1_map<<<g1, TB, 0, stream>>>(abd, lbl, pbd, plog, keys, cep, pl, pc, pcnt);
  k2_select<<<BB, K2T, 0, stream>>>(keys, cep, pl, pc, pcnt, row_loc, row_conf, row_pos);
  k3_final<<<1, 64, 0, stream>>>(row_loc, row_conf, row_pos, (float*)d_out);
}